// Round 1
// baseline (286.621 us; speedup 1.0000x reference)
//
#include <hip/hip_runtime.h>

typedef unsigned short u16;
typedef __bf16 bf16x8 __attribute__((ext_vector_type(8)));
typedef float f32x4 __attribute__((ext_vector_type(4)));

// Problem constants
#define M_DIM 8192      // BATCH*SEQ
#define K_DIM 1024      // MAX_D_IN
#define N_EFF 3072      // nonzero output columns
#define N_FULL 6144     // MAX_D_OUT
#define BM 256
#define BN 128
#define BK 64
#define NKT (K_DIM / BK)   // 16 K-tiles

// ---- helpers ----------------------------------------------------------------
__device__ __forceinline__ u16 f2bf_rne(float f) {
    unsigned u = __float_as_uint(f);
    u += 0x7fffu + ((u >> 16) & 1u);
    return (u16)(u >> 16);
}

__device__ __forceinline__ void gld_lds16(const u16* g, u16* l) {
    // async global->LDS, 16B/lane; LDS dest is wave-uniform base + lane*16.
    __builtin_amdgcn_global_load_lds(
        (const __attribute__((address_space(1))) unsigned int*)g,
        (__attribute__((address_space(3))) unsigned int*)l, 16, 0, 0);
}

// ---- prep: x fp32 -> bf16 ---------------------------------------------------
__global__ void cvt_x(const float* __restrict__ in, u16* __restrict__ out, int n8) {
    int i = blockIdx.x * 256 + threadIdx.x;
    if (i >= n8) return;
    const float4* p = reinterpret_cast<const float4*>(in) + 2 * (size_t)i;
    float4 a = p[0], b = p[1];
    union { u16 h[8]; uint4 v; } r;
    float vals[8] = {a.x, a.y, a.z, a.w, b.x, b.y, b.z, b.w};
#pragma unroll
    for (int j = 0; j < 8; j++) r.h[j] = f2bf_rne(vals[j]);
    reinterpret_cast<uint4*>(out)[i] = r.v;
}

// ---- prep: W_mix = W * M(o,i) -> bf16 (rows [0,3072) only) ------------------
__global__ void prep_w(const float* __restrict__ W, const float* __restrict__ wt,
                       u16* __restrict__ Wm, int n8) {
    int i = blockIdx.x * 256 + threadIdx.x;
    if (i >= n8) return;
    float w01 = wt[0] + wt[1], w23 = wt[2] + wt[3], w45 = wt[4] + wt[5];
    int o = i >> 7;              // row (128 chunks of 8 per 1024-wide row)
    int ib = (i & 127) * 8;      // column base
    float s = w45;
    if (o < 2304 && ib < 768) s += w23;
    if (o < 1536 && ib < 512) s += w01;
    const float4* p = reinterpret_cast<const float4*>(W) + 2 * (size_t)i;
    float4 a = p[0], b = p[1];
    union { u16 h[8]; uint4 v; } r;
    float vals[8] = {a.x, a.y, a.z, a.w, b.x, b.y, b.z, b.w};
#pragma unroll
    for (int j = 0; j < 8; j++) r.h[j] = f2bf_rne(vals[j] * s);
    reinterpret_cast<uint4*>(Wm)[i] = r.v;
}

// ---- GEMM: 256x128 tile, 8 waves (4Mx2N, 64x64/wave), 3-deep LDS pipeline ---
// T2: XOR-swizzled LDS (pre-swizzled global src, swizzled ds_read addr).
// T3/T4: stage kt+2 while computing kt; steady-state s_waitcnt vmcnt(6), never 0.
// T5: setprio(1) around each 16-MFMA cluster. Raw s_barrier (no vmcnt drain).
__global__ __launch_bounds__(512, 2) void gemm_bt(
    const u16* __restrict__ A,      // [8192][1024] bf16
    const u16* __restrict__ B,      // [3072][1024] bf16 (row = output col)
    const float* __restrict__ bias, // raw b[6144] fp32
    const float* __restrict__ wt,   // weights[6]
    float* __restrict__ C)          // [8192][6144] fp32
{
    // [buf 0..2][unit: A-half0, A-half1, B][128 rows x 64 bf16] = 144 KB
    __shared__ u16 lds[3][3][8192];

    const int tid  = threadIdx.x;
    const int bx   = blockIdx.x;   // N tile 0..23
    const int by   = blockIdx.y;   // M tile 0..31
    const int lane = tid & 63;
    const int wv   = tid >> 6;
    const int wm   = (wv >> 1) * 64;   // wave M offset in tile (0,64,128,192)
    const int wn   = (wv & 1) * 64;    // wave N offset in tile (0,64)

    // staging geometry: 2 chunks of 16B per thread per 16KB unit; chunk c ->
    // LDS byte c*16 (linear), row = c>>3, colb = (c&7)*16, source column
    // pre-swizzled by ^((row&7)<<4) (involution; read side applies the same).
    const int c0  = tid, c1 = tid + 512;
    const int r0c = c0 >> 3, r1c = c1 >> 3;
    const size_t o0 = (size_t)r0c * 2048 + (((c0 & 7) * 16) ^ ((r0c & 7) << 4));
    const size_t o1 = (size_t)r1c * 2048 + (((c1 & 7) * 16) ^ ((r1c & 7) << 4));
    const int l0 = c0 * 8, l1 = c1 * 8;

    const char* Ab = (const char*)(A + (size_t)by * BM * K_DIM);
    const char* Bb = (const char*)(B + (size_t)bx * BN * K_DIM);

    auto stage_unit = [&](const char* g, u16* l) {
        gld_lds16((const u16*)(g + o0), l + l0);
        gld_lds16((const u16*)(g + o1), l + l1);
    };

    // fragment read geometry (16x16x32: A/B row = lane&15, k = (lane>>4)*8)
    const int r16 = lane & 15;
    const int sx  = (lane & 7) << 4;            // row-dependent swizzle (row%8 == r16%8)
    const int kq0 = (((lane >> 4) << 4)) ^ sx;  // kk=0 column byte; kk=1 is ^64
    const int au  = wm >> 7;                    // which A half-unit
    const int ar0 = wm & 64;                    // row base within half-unit

    int aoff[4], boff[4];
#pragma unroll
    for (int q = 0; q < 4; ++q) {
        aoff[q] = (ar0 + q * 16 + r16) * 128 + kq0;
        boff[q] = (wn  + q * 16 + r16) * 128 + kq0;
    }

    f32x4 acc[4][4] = {};

    // ---- prologue: stage kt0 -> buf0, kt1 -> buf1 (12 issues/thread) -------
    stage_unit(Ab,                lds[0][0]);
    stage_unit(Ab + 262144,       lds[0][1]);   // 128 rows * 2048 B
    stage_unit(Bb,                lds[0][2]);
    stage_unit(Ab + 128,          lds[1][0]);   // kt*BK*2B = 128 B per K-tile
    stage_unit(Ab + 262144 + 128, lds[1][1]);
    stage_unit(Bb + 128,          lds[1][2]);
    asm volatile("s_waitcnt vmcnt(6)" ::: "memory");  // kt0 landed, kt1 in flight
    __builtin_amdgcn_s_barrier();

    int bb = 0;
    for (int t = 0; t < NKT; ++t) {
        const int sb = (bb == 0) ? 2 : bb - 1;  // (bb+2)%3: stage target
        const u16* Au = lds[bb][au];
        const u16* Bu = lds[bb][2];
        const char* Akt = Ab + (size_t)(t + 2) * 128;
        const char* Bkt = Bb + (size_t)(t + 2) * 128;
        const bool st = (t < NKT - 2);
        bf16x8 af[4], bf[4];

        // ===== phase 0: kk=0; prefetch A units of kt+2 =====
        if (st) {
            stage_unit(Akt,          lds[sb][0]);
            stage_unit(Akt + 262144, lds[sb][1]);
        }
#pragma unroll
        for (int q = 0; q < 4; ++q) {
            af[q] = *(const bf16x8*)((const char*)Au + aoff[q]);
            bf[q] = *(const bf16x8*)((const char*)Bu + boff[q]);
        }
        __builtin_amdgcn_s_setprio(1);
#pragma unroll
        for (int tm = 0; tm < 4; ++tm)
#pragma unroll
            for (int tn = 0; tn < 4; ++tn)
                acc[tm][tn] = __builtin_amdgcn_mfma_f32_16x16x32_bf16(
                    af[tm], bf[tn], acc[tm][tn], 0, 0, 0);
        __builtin_amdgcn_s_setprio(0);
        __builtin_amdgcn_s_barrier();

        // ===== phase 1: kk=1; prefetch B unit of kt+2 =====
        if (st) stage_unit(Bkt, lds[sb][2]);
#pragma unroll
        for (int q = 0; q < 4; ++q) {
            af[q] = *(const bf16x8*)((const char*)Au + (aoff[q] ^ 64));
            bf[q] = *(const bf16x8*)((const char*)Bu + (boff[q] ^ 64));
        }
        __builtin_amdgcn_s_setprio(1);
#pragma unroll
        for (int tm = 0; tm < 4; ++tm)
#pragma unroll
            for (int tn = 0; tn < 4; ++tn)
                acc[tm][tn] = __builtin_amdgcn_mfma_f32_16x16x32_bf16(
                    af[tm], bf[tn], acc[tm][tn], 0, 0, 0);
        __builtin_amdgcn_s_setprio(0);
        // ledger: outstanding = kt(t+1)'s 6 (oldest) + kt(t+2)'s 6 -> wait to 6
        // retires kt(t+1) exactly; tail iterations drain fully.
        if (st) asm volatile("s_waitcnt vmcnt(6)" ::: "memory");
        else    asm volatile("s_waitcnt vmcnt(0)" ::: "memory");
        __builtin_amdgcn_s_barrier();

        bb = (bb == 2) ? 0 : bb + 1;
    }

    // ---- epilogue: fused bias, C/D layout col=lane&15 (n), row=(lane>>4)*4+r
    const float w01 = wt[0] + wt[1], w23 = wt[2] + wt[3], w45 = wt[4] + wt[5];
    const int m0 = by * BM + wm + (lane >> 4) * 4;
    const int n0 = bx * BN + wn + r16;
#pragma unroll
    for (int tn = 0; tn < 4; ++tn) {
        int n = n0 + tn * 16;
        float s = w45 + (n < 2304 ? w23 : 0.f) + (n < 1536 ? w01 : 0.f);
        float bv = bias[n] * s;
#pragma unroll
        for (int tm = 0; tm < 4; ++tm) {
            int m = m0 + tm * 16;
#pragma unroll
            for (int r = 0; r < 4; ++r)
                __builtin_nontemporal_store(acc[tm][tn][r] + bv,
                    &C[(size_t)(m + r) * N_FULL + n]);
        }
    }

    // Zero-fill mirror tile at columns [3072+bx*128, +128) for rows [by*256,+256)
    const f32x4 z = {0.f, 0.f, 0.f, 0.f};
#pragma unroll
    for (int it = 0; it < 16; ++it) {
        int lin = it * 512 + tid;        // 0..8191 -> 256 rows x 32 float4
        int row = lin >> 5;
        int c4  = (lin & 31) * 4;
        __builtin_nontemporal_store(z, reinterpret_cast<f32x4*>(
            &C[(size_t)(by * BM + row) * N_FULL + N_EFF + bx * BN + c4]));
    }
}

// ---- launch -----------------------------------------------------------------
extern "C" void kernel_launch(void* const* d_in, const int* in_sizes, int n_in,
                              void* d_out, int out_size, void* d_ws, size_t ws_size,
                              hipStream_t stream) {
    const float* x   = (const float*)d_in[0];  // [8,1024,1024]
    const float* wts = (const float*)d_in[1];  // [6]
    const float* W   = (const float*)d_in[2];  // [6144,1024]
    const float* b   = (const float*)d_in[3];  // [6144]
    float* out = (float*)d_out;                // [8192,6144]

    // workspace: xb 16 MB | Wm 6 MB
    u16* xb = (u16*)d_ws;
    u16* Wm = (u16*)((char*)d_ws + 16777216);

    cvt_x <<<4096, 256, 0, stream>>>(x, xb, M_DIM * K_DIM / 8);
    prep_w<<<1536, 256, 0, stream>>>(W, wts, Wm, N_EFF * K_DIM / 8);
    gemm_bt<<<dim3(N_EFF / BN, M_DIM / BM), 512, 0, stream>>>(xb, Wm, b, wts, out);
}

// Round 2
// 281.691 us; speedup vs baseline: 1.0175x; 1.0175x over previous
//
#include <hip/hip_runtime.h>

typedef unsigned short u16;
typedef __bf16 bf16x8 __attribute__((ext_vector_type(8)));
typedef float f32x4 __attribute__((ext_vector_type(4)));

// Problem constants
#define M_DIM 8192      // BATCH*SEQ
#define K_DIM 1024      // MAX_D_IN
#define N_EFF 3072      // nonzero output columns
#define N_FULL 6144     // MAX_D_OUT
#define BM 128
#define BN 128
#define BK 32           // per sub-tile; 2 sub-tiles staged per barrier

// ---- helpers ----------------------------------------------------------------
__device__ __forceinline__ u16 f2bf_rne(float f) {
    unsigned u = __float_as_uint(f);
    u += 0x7fffu + ((u >> 16) & 1u);
    return (u16)(u >> 16);
}

__device__ __forceinline__ void gld_lds16(const u16* g, u16* l) {
    // async global->LDS, 16B per lane; LDS dest = wave-uniform base + lane*16,
    // our chunk indexing keeps lane-order == contiguous LDS order.
    __builtin_amdgcn_global_load_lds(
        (const __attribute__((address_space(1))) unsigned int*)g,
        (__attribute__((address_space(3))) unsigned int*)l, 16, 0, 0);
}

// ---- prep (fused): x fp32->bf16  AND  W_mix = W*M -> bf16 -------------------
// Independent producers; one dispatch lets them run concurrently (max(8,3) us
// instead of 8+3 serialized) and saves a graph node.
// blocks [0,4096): cvt_x over 1,048,576 chunks (exact, no guard)
// blocks [4096,5632): prep_w over 393,216 chunks (exact, no guard)
__global__ void prep_all(const float* __restrict__ x, u16* __restrict__ xb,
                         const float* __restrict__ W, const float* __restrict__ wt,
                         u16* __restrict__ Wm) {
    const int b = blockIdx.x;
    if (b < 4096) {
        int i = b * 256 + threadIdx.x;
        const float4* p = reinterpret_cast<const float4*>(x) + 2 * (size_t)i;
        float4 a = p[0], c = p[1];
        union { u16 h[8]; uint4 v; } r;
        float vals[8] = {a.x, a.y, a.z, a.w, c.x, c.y, c.z, c.w};
#pragma unroll
        for (int j = 0; j < 8; j++) r.h[j] = f2bf_rne(vals[j]);
        reinterpret_cast<uint4*>(xb)[i] = r.v;
    } else {
        int i = (b - 4096) * 256 + threadIdx.x;
        float w01 = wt[0] + wt[1], w23 = wt[2] + wt[3], w45 = wt[4] + wt[5];
        int o = i >> 7;              // row (128 chunks of 8 per 1024-wide row)
        int ib = (i & 127) * 8;      // column base; 512/768 are multiples of 8
        float s = w45;
        if (o < 2304 && ib < 768) s += w23;
        if (o < 1536 && ib < 512) s += w01;
        const float4* p = reinterpret_cast<const float4*>(W) + 2 * (size_t)i;
        float4 a = p[0], c = p[1];
        union { u16 h[8]; uint4 v; } r;
        float vals[8] = {a.x, a.y, a.z, a.w, c.x, c.y, c.z, c.w};
#pragma unroll
        for (int j = 0; j < 8; j++) r.h[j] = f2bf_rne(vals[j] * s);
        reinterpret_cast<uint4*>(Wm)[i] = r.v;
    }
}

// ---- GEMM: C[m,n] = sum_k A[m,k]*B[n,k] + b[n]*s(n); zero-fills n+3072 ------
// m97 recipe, 2x BK=32 sub-tiles staged per barrier. 32 KB LDS -> 3 blocks/CU
// (launch_bounds(256,3)): block-level epilogue-write / compute overlap is what
// keeps the kernel at the C-write roofline (~30 us for 201 MB).
__global__ __launch_bounds__(256, 3) void gemm_bt(
    const u16* __restrict__ A,   // [8192][1024] bf16
    const u16* __restrict__ B,   // [3072][1024] bf16 (row = output col)
    const float* __restrict__ bias, // raw b[6144] fp32
    const float* __restrict__ wt,   // weights[6]
    float* __restrict__ C)       // [8192][6144] fp32
{
    __shared__ u16 As[2 * BM * BK];  // 16 KB: sub-tile st at offset st*4096
    __shared__ u16 Bs[2 * BN * BK];  // 16 KB

    const int tid  = threadIdx.x;
    const int bx   = blockIdx.x;   // N tile 0..23
    const int by   = blockIdx.y;   // M tile 0..63
    const int lane = tid & 63;
    const int wv   = tid >> 6;
    const int wm   = (wv >> 1) * 64;  // wave row offset in tile
    const int wn   = (wv & 1) * 64;   // wave col offset in tile

    f32x4 acc[4][4] = {};

    const u16* Ag = A + (size_t)(by * BM) * K_DIM;
    const u16* Bg = B + (size_t)(bx * BN) * K_DIM;

    const int kq  = (lane >> 4) * 8;  // k offset of this lane's fragment
    const int r16 = lane & 15;

    for (int kt = 0; kt < K_DIM; kt += 2 * BK) {
        __syncthreads();  // protect previous iteration's LDS reads
#pragma unroll
        for (int u = 0; u < 4; u++) {
            int c  = u * 256 + tid;        // chunk index 0..1023, 16B each
            int st = c >> 9;               // sub-tile 0/1
            int c2 = c & 511;
            int row = c2 >> 2, kc = (c2 & 3) * 8;
            size_t goff = (size_t)row * K_DIM + kt + st * BK + kc;
            gld_lds16(Ag + goff, &As[c * 8]);
            gld_lds16(Bg + goff, &Bs[c * 8]);
        }
        __syncthreads();  // drains vmcnt before reads

#pragma unroll
        for (int st = 0; st < 2; st++) {
            bf16x8 af[4], bf[4];
#pragma unroll
            for (int t = 0; t < 4; t++) {
                af[t] = *reinterpret_cast<const bf16x8*>(
                    &As[st * 4096 + (wm + t * 16 + r16) * BK + kq]);
                bf[t] = *reinterpret_cast<const bf16x8*>(
                    &Bs[st * 4096 + (wn + t * 16 + r16) * BK + kq]);
            }
#pragma unroll
            for (int tm = 0; tm < 4; tm++)
#pragma unroll
                for (int tn = 0; tn < 4; tn++)
                    acc[tm][tn] = __builtin_amdgcn_mfma_f32_16x16x32_bf16(
                        af[tm], bf[tn], acc[tm][tn], 0, 0, 0);
        }
    }

    // Fused bias: s(n) = w45 + (n<2304)*w23 + (n<1536)*w01
    const float w01 = wt[0] + wt[1], w23 = wt[2] + wt[3], w45 = wt[4] + wt[5];

    // Epilogue: C/D layout col=lane&15 (n), row=(lane>>4)*4+reg (m).
    const int m0 = by * BM + wm + (lane >> 4) * 4;
    const int n0 = bx * BN + wn + (lane & 15);
#pragma unroll
    for (int tn = 0; tn < 4; tn++) {
        int n = n0 + tn * 16;
        float s = w45 + (n < 2304 ? w23 : 0.f) + (n < 1536 ? w01 : 0.f);
        float bv = bias[n] * s;
#pragma unroll
        for (int tm = 0; tm < 4; tm++) {
            int m = m0 + tm * 16;
#pragma unroll
            for (int r = 0; r < 4; r++)
                __builtin_nontemporal_store(acc[tm][tn][r] + bv,
                    &C[(size_t)(m + r) * N_FULL + n]);
        }
    }

    // Zero-fill the mirror tile at columns [3072+bx*128, +128): exact zeros in ref.
    const f32x4 z = {0.f, 0.f, 0.f, 0.f};
#pragma unroll
    for (int it = 0; it < 16; it++) {
        int lin = it * 256 + tid;        // 0..4095 -> 128 rows x 32 float4
        int row = lin >> 5;
        int c4  = (lin & 31) * 4;
        __builtin_nontemporal_store(z, reinterpret_cast<f32x4*>(
            &C[(size_t)(by * BM + row) * N_FULL + N_EFF + bx * BN + c4]));
    }
}

// ---- launch -----------------------------------------------------------------
extern "C" void kernel_launch(void* const* d_in, const int* in_sizes, int n_in,
                              void* d_out, int out_size, void* d_ws, size_t ws_size,
                              hipStream_t stream) {
    const float* x   = (const float*)d_in[0];  // [8,1024,1024]
    const float* wts = (const float*)d_in[1];  // [6]
    const float* W   = (const float*)d_in[2];  // [6144,1024]
    const float* b   = (const float*)d_in[3];  // [6144]
    float* out = (float*)d_out;                // [8192,6144]

    // workspace: xb 16 MB | Wm 6 MB
    u16* xb = (u16*)d_ws;
    u16* Wm = (u16*)((char*)d_ws + 16777216);

    prep_all<<<5632, 256, 0, stream>>>(x, xb, W, wts, Wm);
    gemm_bt<<<dim3(N_EFF / BN, M_DIM / BM), 256, 0, stream>>>(xb, Wm, b, wts, out);
}